// Round 9
// baseline (163.772 us; speedup 1.0000x reference)
//
#include <hip/hip_runtime.h>
#include <hip/hip_fp16.h>

#define NN 50000
#define NE 800000
#define D 64
#define GB ((NN + 63) / 64)       // 782 gemm blocks
#define NBUCK ((NN + 127) >> 7)   // 391 buckets of 128 dst nodes
#define CHUNK 4096
#define EBLKS ((NE + CHUNK - 1) / CHUNK)
#define CAPB 4096                 // per-bucket capacity (mean 2046, sd 45 -> +45 sigma)

__device__ __forceinline__ float lrelu(float s) { return (s > 0.0f) ? s : 0.2f * s; }

// ---------------- CSR build (once per launch; edges shared by all 3 layers) --------------

// Phase B: bin edges into fixed-capacity 128-node buckets (no pre-histogram needed).
// Packed u32 (src<<7 | dst&127); per-block contiguous runs -> coalesced writes.
__global__ __launch_bounds__(256) void bin_pass(const int* __restrict__ ei,
                                                int* __restrict__ gcur,
                                                unsigned* __restrict__ pairs) {
  __shared__ int cnt_loc[NBUCK];
  __shared__ int base_loc[NBUCK];
  int t = threadIdx.x;
  int e0 = blockIdx.x * CHUNK;
  int n = (NE - e0 < CHUNK) ? (NE - e0) : CHUNK;
  for (int i = t; i < NBUCK; i += 256) cnt_loc[i] = 0;
  __syncthreads();
  for (int i = t; i < n; i += 256)
    atomicAdd(&cnt_loc[ei[NE + e0 + i] >> 7], 1);
  __syncthreads();
  for (int i = t; i < NBUCK; i += 256) {
    int c = cnt_loc[i];
    base_loc[i] = c ? (i * CAPB + atomicAdd(&gcur[i], c)) : 0;
    cnt_loc[i] = 0;
  }
  __syncthreads();
  for (int i = t; i < n; i += 256) {
    int src = ei[e0 + i];
    int dst = ei[NE + e0 + i];
    int b = dst >> 7;
    int off = atomicAdd(&cnt_loc[b], 1);
    unsigned pk = ((unsigned)src << 7) | (unsigned)(dst & 127);
    __builtin_nontemporal_store(pk, &pairs[base_loc[b] + off]);
  }
}

// Phase C: per-bucket exact sort in LDS; emits row_start + deg (padded bucket layout).
__global__ __launch_bounds__(256) void bucket_sort(const unsigned* __restrict__ pairs,
                                                   const int* __restrict__ gcur,
                                                   int* __restrict__ row_start,
                                                   int* __restrict__ deg,
                                                   int* __restrict__ sorted_src) {
  __shared__ int cnt[128];
  __shared__ int exc[128];
  __shared__ int cur[128];
  __shared__ int buf[CAPB];
  int b = blockIdx.x;
  int t = threadIdx.x;
  int n0 = b << 7;
  int start = b * CAPB;
  int cntb = gcur[b];
  if (cntb > CAPB) cntb = CAPB;
  if (t < 128) cnt[t] = 0;
  __syncthreads();
  for (int i = t; i < cntb; i += 256)
    atomicAdd(&cnt[pairs[start + i] & 127u], 1);
  __syncthreads();
  if (t < 128) exc[t] = cnt[t];
  __syncthreads();
  for (int s = 1; s < 128; s <<= 1) {
    int add = 0;
    if (t < 128 && t >= s) add = exc[t - s];
    __syncthreads();
    if (t < 128) exc[t] += add;
    __syncthreads();
  }
  if (t < 128) {
    int e = exc[t] - cnt[t];   // exclusive prefix within bucket
    cur[t] = e;
    int nd = n0 + t;
    if (nd < NN) {
      row_start[nd] = start + e;
      deg[nd] = cnt[t];
    }
  }
  __syncthreads();
  for (int i = t; i < cntb; i += 256) {
    unsigned pk = pairs[start + i];
    int pos = atomicAdd(&cur[pk & 127u], 1);
    if (pos < CAPB) buf[pos] = (int)(pk >> 7);
  }
  __syncthreads();
  for (int i = t; i < cntb; i += 256)
    sorted_src[start + i] = buf[i];
}

// ---------------- per-layer kernels --------------------------------------------------

// 64-node tile GEMM, 4x4 register blocking, transposed-x LDS staging.
__global__ __launch_bounds__(256) void gemm_feat(
    const float* __restrict__ xin, const float* __restrict__ W,
    const float* __restrict__ a_src, const float* __restrict__ a_dst,
    __half* __restrict__ h16, float* __restrict__ s_src, float* __restrict__ s_dst,
    int do_relu) {
  __shared__ float wlds[64 * 64];
  __shared__ float xT[64][68];
  __shared__ float psrc[64][17];
  __shared__ float pdst[64][17];
  int t = threadIdx.x;
  int n0 = blockIdx.x * 64;

  const float4* W4 = (const float4*)W;
  float4* wl4 = (float4*)wlds;
#pragma unroll
  for (int i = 0; i < 4; ++i) wl4[t + 256 * i] = W4[t + 256 * i];

#pragma unroll
  for (int i = 0; i < 4; ++i) {
    int idx = t + 256 * i;
    int r = idx >> 4, c4 = idx & 15;
    int n = n0 + r;
    float4 v = make_float4(0.f, 0.f, 0.f, 0.f);
    if (n < NN) v = ((const float4*)xin)[(size_t)n * 16 + c4];
    if (do_relu) {
      v.x = fmaxf(v.x, 0.f); v.y = fmaxf(v.y, 0.f);
      v.z = fmaxf(v.z, 0.f); v.w = fmaxf(v.w, 0.f);
    }
    xT[c4 * 4 + 0][r] = v.x;
    xT[c4 * 4 + 1][r] = v.y;
    xT[c4 * 4 + 2][r] = v.z;
    xT[c4 * 4 + 3][r] = v.w;
  }
  __syncthreads();

  int tr = t & 15, tc = t >> 4;   // nodes tr*4..+3, cols tc*4..+3
  float acc[4][4] = {};
#pragma unroll 8
  for (int k = 0; k < 64; ++k) {
    float4 xa = *(const float4*)&xT[k][tr * 4];
    float4 wv = *(const float4*)&wlds[k * 64 + tc * 4];
    float xs[4] = {xa.x, xa.y, xa.z, xa.w};
    float wj[4] = {wv.x, wv.y, wv.z, wv.w};
#pragma unroll
    for (int i = 0; i < 4; ++i)
#pragma unroll
      for (int j = 0; j < 4; ++j) acc[i][j] = fmaf(xs[i], wj[j], acc[i][j]);
  }

#pragma unroll
  for (int i = 0; i < 4; ++i) {
    int n = n0 + tr * 4 + i;
    if (n < NN) {
      __half2* dst = (__half2*)&h16[(size_t)n * 64 + tc * 4];
      dst[0] = __floats2half2_rn(acc[i][0], acc[i][1]);
      dst[1] = __floats2half2_rn(acc[i][2], acc[i][3]);
    }
  }

  float as[4], ad[4];
#pragma unroll
  for (int j = 0; j < 4; ++j) { as[j] = a_src[tc * 4 + j]; ad[j] = a_dst[tc * 4 + j]; }
#pragma unroll
  for (int i = 0; i < 4; ++i) {
    float p1 = 0.f, p2 = 0.f;
#pragma unroll
    for (int j = 0; j < 4; ++j) { p1 = fmaf(acc[i][j], as[j], p1); p2 = fmaf(acc[i][j], ad[j], p2); }
    psrc[tr * 4 + i][tc] = p1;
    pdst[tr * 4 + i][tc] = p2;
  }
  __syncthreads();
  if (t < 64) {
    int n = n0 + t;
    if (n < NN) {
      float s1 = 0.f, s2 = 0.f;
#pragma unroll
      for (int c = 0; c < 16; ++c) { s1 += psrc[t][c]; s2 += pdst[t][c]; }
      s_src[n] = s1;
      s_dst[n] = s2;
    }
  }
}

// FOUR nodes per wave: each 16-lane group owns one dst node; lane handles 4 features
// (8 B). One wave-wide VMEM gather serves four edge rows; width-16 shfl broadcasts
// serve 4 edges each. Same proven group-per-node structure as R7/R8.
__global__ void agg_kernel(const int* __restrict__ sorted_src, const int* __restrict__ row_start,
                           const int* __restrict__ deg, const float* __restrict__ s_src,
                           const float* __restrict__ s_dst, const __half* __restrict__ h16,
                           const float* __restrict__ bias, float* __restrict__ out) {
  int gid = blockIdx.x * blockDim.x + threadIdx.x;
  int n = gid >> 4;
  if (n >= NN) return;
  int lane = threadIdx.x & 15;   // lane within the 16-lane group
  int start = row_start[n];
  int dg = deg[n];
  float sdn = s_dst[n];
  float sself = lrelu(s_src[n] + sdn);
  float exself = __expf(sself - 8.0f);

  float4 acc;
  {
    uint2 hv = *(const uint2*)&h16[(size_t)n * 64 + 4 * lane];
    float2 f0 = __half22float2(*(__half2*)&hv.x);
    float2 f1 = __half22float2(*(__half2*)&hv.y);
    acc.x = exself * f0.x;
    acc.y = exself * f0.y;
    acc.z = exself * f1.x;
    acc.w = exself * f1.y;
  }
  float dpart = 0.0f;
  for (int base = 0; base < dg; base += 16) {
    int i = base + lane;
    bool act = (i < dg);
    int msrc = act ? __builtin_nontemporal_load(&sorted_src[start + i]) : 0;
    float s = act ? lrelu(s_src[msrc] + sdn) : -INFINITY;
    float ex = __expf(s - 8.0f);   // 0 for inactive lanes
    dpart += ex;
    int nch = (dg - base < 16) ? (dg - base) : 16;
    for (int b0 = 0; b0 < nch; b0 += 8) {
      float xs[8]; int ss[8]; uint2 vv[8];
#pragma unroll
      for (int e = 0; e < 8; ++e) {
        xs[e] = __shfl(ex, b0 + e, 16);
        ss[e] = __shfl(msrc, b0 + e, 16);
      }
#pragma unroll
      for (int e = 0; e < 8; ++e)
        vv[e] = *(const uint2*)&h16[(size_t)ss[e] * 64 + 4 * lane];
#pragma unroll
      for (int e = 0; e < 8; ++e) {
        float2 f0 = __half22float2(*(__half2*)&vv[e].x);
        float2 f1 = __half22float2(*(__half2*)&vv[e].y);
        acc.x = fmaf(xs[e], f0.x, acc.x);
        acc.y = fmaf(xs[e], f0.y, acc.y);
        acc.z = fmaf(xs[e], f1.x, acc.z);
        acc.w = fmaf(xs[e], f1.y, acc.w);
      }
    }
  }
#pragma unroll
  for (int off = 8; off > 0; off >>= 1)
    dpart += __shfl_xor(dpart, off, 16);
  float d = exself + dpart;
  float4 bv = *(const float4*)&bias[4 * lane];
  float4 o;
  o.x = acc.x / d + bv.x;
  o.y = acc.y / d + bv.y;
  o.z = acc.z / d + bv.z;
  o.w = acc.w / d + bv.w;
  *(float4*)&out[(size_t)n * 64 + 4 * lane] = o;
}

// ---------------- host-side orchestration --------------------------------------------

static void run_layer(const float* xin, int do_relu, const float* W, const float* a_src,
                      const float* a_dst, const float* b, const int* sorted_src,
                      const int* row_start, const int* deg, __half* h16, float* s_src,
                      float* s_dst, float* out, hipStream_t stream) {
  gemm_feat<<<GB, 256, 0, stream>>>(xin, W, a_src, a_dst, h16, s_src, s_dst, do_relu);
  agg_kernel<<<(NN * 16 + 255) / 256, 256, 0, stream>>>(sorted_src, row_start, deg, s_src,
                                                        s_dst, h16, b, out);
}

extern "C" void kernel_launch(void* const* d_in, const int* in_sizes, int n_in,
                              void* d_out, int out_size, void* d_ws, size_t ws_size,
                              hipStream_t stream) {
  const float* x  = (const float*)d_in[1];
  const int*   ei = (const int*)d_in[2];
  const float* W1 = (const float*)d_in[3];
  const float* as1 = (const float*)d_in[4];
  const float* ad1 = (const float*)d_in[5];
  const float* b1 = (const float*)d_in[6];
  const float* W2 = (const float*)d_in[7];
  const float* as2 = (const float*)d_in[8];
  const float* ad2 = (const float*)d_in[9];
  const float* b2 = (const float*)d_in[10];
  const float* W3 = (const float*)d_in[11];
  const float* as3 = (const float*)d_in[12];
  const float* ad3 = (const float*)d_in[13];
  const float* b3 = (const float*)d_in[14];
  float* out = (float*)d_out;

  const size_t ND = (size_t)NN * D;
  char* base = (char*)d_ws;
  __half* h16    = (__half*)base;                    // ND halves = 6.4 MB
  float* A       = (float*)(base + ND * 2);          // ND floats (12.8 MB)
  float* B       = A + ND;                           // ND floats
  float* s_src   = B + ND;                           // NN
  float* s_dst   = s_src + NN;                       // NN
  int* row_start = (int*)(s_dst + NN);               // NN
  int* deg       = row_start + NN;                   // NN
  int* gcur      = deg + NN;                         // NBUCK
  int* sorted_src= gcur + NBUCK;                     // NBUCK*CAPB = 6.4 MB
  // pairs aliases A: only live during CSR build, before layer 1 writes A.
  unsigned* pairs = (unsigned*)A;                    // NBUCK*CAPB u32 = 6.4 MB (A is 12.8 MB)

  // ---- CSR build (edges identical across layers) ----
  hipMemsetAsync(gcur, 0, (size_t)NBUCK * sizeof(int), stream);
  bin_pass<<<EBLKS, 256, 0, stream>>>(ei, gcur, pairs);
  bucket_sort<<<NBUCK, 256, 0, stream>>>(pairs, gcur, row_start, deg, sorted_src);

  // ---- 3 GAT layers ----
  run_layer(x, 0, W1, as1, ad1, b1, sorted_src, row_start, deg, h16, s_src, s_dst, A, stream);
  run_layer(A, 1, W2, as2, ad2, b2, sorted_src, row_start, deg, h16, s_src, s_dst, B, stream);
  run_layer(B, 1, W3, as3, ad3, b3, sorted_src, row_start, deg, h16, s_src, s_dst, out, stream);
}

// Round 10
// 149.786 us; speedup vs baseline: 1.0934x; 1.0934x over previous
//
#include <hip/hip_runtime.h>
#include <hip/hip_fp16.h>

#define NN 50000
#define NE 800000
#define D 64
#define GB ((NN + 63) / 64)       // 782 gemm blocks
#define NBUCK ((NN + 127) >> 7)   // 391 buckets of 128 dst nodes
#define CHUNK 4096
#define EBLKS ((NE + CHUNK - 1) / CHUNK)   // 196 bin blocks
#define CAPB 4096                 // per-bucket capacity (mean 2046, sd 45 -> +45 sigma)

__device__ __forceinline__ float lrelu(float s) { return (s > 0.0f) ? s : 0.2f * s; }

// ---------------- device bodies (shared by fused and standalone kernels) --------------

__device__ __forceinline__ void bin_pass_body(int blk, const int* __restrict__ ei,
                                              int* __restrict__ gcur,
                                              unsigned* __restrict__ pairs,
                                              int* cnt_loc, int* base_loc) {
  int t = threadIdx.x;
  int e0 = blk * CHUNK;
  int n = (NE - e0 < CHUNK) ? (NE - e0) : CHUNK;
  for (int i = t; i < NBUCK; i += 256) cnt_loc[i] = 0;
  __syncthreads();
  for (int i = t; i < n; i += 256)
    atomicAdd(&cnt_loc[ei[NE + e0 + i] >> 7], 1);
  __syncthreads();
  for (int i = t; i < NBUCK; i += 256) {
    int c = cnt_loc[i];
    base_loc[i] = c ? (i * CAPB + atomicAdd(&gcur[i], c)) : 0;
    cnt_loc[i] = 0;
  }
  __syncthreads();
  for (int i = t; i < n; i += 256) {
    int src = ei[e0 + i];
    int dst = ei[NE + e0 + i];
    int b = dst >> 7;
    int off = atomicAdd(&cnt_loc[b], 1);
    unsigned pk = ((unsigned)src << 7) | (unsigned)(dst & 127);
    __builtin_nontemporal_store(pk, &pairs[base_loc[b] + off]);
  }
}

__device__ __forceinline__ void gemm_body(int gblk, const float* __restrict__ xin,
                                          const float* __restrict__ W,
                                          const float* __restrict__ a_src,
                                          const float* __restrict__ a_dst,
                                          __half* __restrict__ h16,
                                          float* __restrict__ s_src,
                                          float* __restrict__ s_dst, int do_relu,
                                          float* wlds, float (*xT)[68],
                                          float (*psrc)[17], float (*pdst)[17]) {
  int t = threadIdx.x;
  int n0 = gblk * 64;

  const float4* W4 = (const float4*)W;
  float4* wl4 = (float4*)wlds;
#pragma unroll
  for (int i = 0; i < 4; ++i) wl4[t + 256 * i] = W4[t + 256 * i];

#pragma unroll
  for (int i = 0; i < 4; ++i) {
    int idx = t + 256 * i;
    int r = idx >> 4, c4 = idx & 15;
    int n = n0 + r;
    float4 v = make_float4(0.f, 0.f, 0.f, 0.f);
    if (n < NN) v = ((const float4*)xin)[(size_t)n * 16 + c4];
    if (do_relu) {
      v.x = fmaxf(v.x, 0.f); v.y = fmaxf(v.y, 0.f);
      v.z = fmaxf(v.z, 0.f); v.w = fmaxf(v.w, 0.f);
    }
    xT[c4 * 4 + 0][r] = v.x;
    xT[c4 * 4 + 1][r] = v.y;
    xT[c4 * 4 + 2][r] = v.z;
    xT[c4 * 4 + 3][r] = v.w;
  }
  __syncthreads();

  int tr = t & 15, tc = t >> 4;   // nodes tr*4..+3, cols tc*4..+3
  float acc[4][4] = {};
#pragma unroll 8
  for (int k = 0; k < 64; ++k) {
    float4 xa = *(const float4*)&xT[k][tr * 4];
    float4 wv = *(const float4*)&wlds[k * 64 + tc * 4];
    float xs[4] = {xa.x, xa.y, xa.z, xa.w};
    float wj[4] = {wv.x, wv.y, wv.z, wv.w};
#pragma unroll
    for (int i = 0; i < 4; ++i)
#pragma unroll
      for (int j = 0; j < 4; ++j) acc[i][j] = fmaf(xs[i], wj[j], acc[i][j]);
  }

#pragma unroll
  for (int i = 0; i < 4; ++i) {
    int n = n0 + tr * 4 + i;
    if (n < NN) {
      __half2* dst = (__half2*)&h16[(size_t)n * 64 + tc * 4];
      dst[0] = __floats2half2_rn(acc[i][0], acc[i][1]);
      dst[1] = __floats2half2_rn(acc[i][2], acc[i][3]);
    }
  }

  float as[4], ad[4];
#pragma unroll
  for (int j = 0; j < 4; ++j) { as[j] = a_src[tc * 4 + j]; ad[j] = a_dst[tc * 4 + j]; }
#pragma unroll
  for (int i = 0; i < 4; ++i) {
    float p1 = 0.f, p2 = 0.f;
#pragma unroll
    for (int j = 0; j < 4; ++j) { p1 = fmaf(acc[i][j], as[j], p1); p2 = fmaf(acc[i][j], ad[j], p2); }
    psrc[tr * 4 + i][tc] = p1;
    pdst[tr * 4 + i][tc] = p2;
  }
  __syncthreads();
  if (t < 64) {
    int n = n0 + t;
    if (n < NN) {
      float s1 = 0.f, s2 = 0.f;
#pragma unroll
      for (int c = 0; c < 16; ++c) { s1 += psrc[t][c]; s2 += pdst[t][c]; }
      s_src[n] = s1;
      s_dst[n] = s2;
    }
  }
}

// ---------------- kernels --------------------------------------------------

// Fused: blocks [0,EBLKS) bin the edge list; blocks [EBLKS, EBLKS+GB) run layer-1 GEMM.
// The two tasks are independent (edges vs x@W1) and co-schedule across CUs.
__global__ __launch_bounds__(256) void bin_gemm1(
    const int* __restrict__ ei, int* __restrict__ gcur, unsigned* __restrict__ pairs,
    const float* __restrict__ xin, const float* __restrict__ W,
    const float* __restrict__ a_src, const float* __restrict__ a_dst,
    __half* __restrict__ h16, float* __restrict__ s_src, float* __restrict__ s_dst) {
  __shared__ float wlds[64 * 64];
  __shared__ float xT[64][68];
  __shared__ float psrc[64][17];
  __shared__ float pdst[64][17];
  __shared__ int cnt_loc[NBUCK];
  __shared__ int base_loc[NBUCK];
  if (blockIdx.x < EBLKS) {
    bin_pass_body(blockIdx.x, ei, gcur, pairs, cnt_loc, base_loc);
  } else {
    gemm_body(blockIdx.x - EBLKS, xin, W, a_src, a_dst, h16, s_src, s_dst, 0,
              wlds, xT, psrc, pdst);
  }
}

// Standalone GEMM for layers 2-3.
__global__ __launch_bounds__(256) void gemm_feat(
    const float* __restrict__ xin, const float* __restrict__ W,
    const float* __restrict__ a_src, const float* __restrict__ a_dst,
    __half* __restrict__ h16, float* __restrict__ s_src, float* __restrict__ s_dst,
    int do_relu) {
  __shared__ float wlds[64 * 64];
  __shared__ float xT[64][68];
  __shared__ float psrc[64][17];
  __shared__ float pdst[64][17];
  gemm_body(blockIdx.x, xin, W, a_src, a_dst, h16, s_src, s_dst, do_relu,
            wlds, xT, psrc, pdst);
}

// Phase C: per-bucket exact sort in LDS; emits row_start + deg (padded bucket layout).
__global__ __launch_bounds__(256) void bucket_sort(const unsigned* __restrict__ pairs,
                                                   const int* __restrict__ gcur,
                                                   int* __restrict__ row_start,
                                                   int* __restrict__ deg,
                                                   int* __restrict__ sorted_src) {
  __shared__ int cnt[128];
  __shared__ int exc[128];
  __shared__ int cur[128];
  __shared__ int buf[CAPB];
  int b = blockIdx.x;
  int t = threadIdx.x;
  int n0 = b << 7;
  int start = b * CAPB;
  int cntb = gcur[b];
  if (cntb > CAPB) cntb = CAPB;
  if (t < 128) cnt[t] = 0;
  __syncthreads();
  for (int i = t; i < cntb; i += 256)
    atomicAdd(&cnt[pairs[start + i] & 127u], 1);
  __syncthreads();
  if (t < 128) exc[t] = cnt[t];
  __syncthreads();
  for (int s = 1; s < 128; s <<= 1) {
    int add = 0;
    if (t < 128 && t >= s) add = exc[t - s];
    __syncthreads();
    if (t < 128) exc[t] += add;
    __syncthreads();
  }
  if (t < 128) {
    int e = exc[t] - cnt[t];   // exclusive prefix within bucket
    cur[t] = e;
    int nd = n0 + t;
    if (nd < NN) {
      row_start[nd] = start + e;
      deg[nd] = cnt[t];
    }
  }
  __syncthreads();
  for (int i = t; i < cntb; i += 256) {
    unsigned pk = pairs[start + i];
    int pos = atomicAdd(&cur[pk & 127u], 1);
    if (pos < CAPB) buf[pos] = (int)(pk >> 7);
  }
  __syncthreads();
  for (int i = t; i < cntb; i += 256)
    sorted_src[start + i] = buf[i];
}

// TWO nodes per wave (R8-proven): each 32-lane group owns one dst node; lane = half2
// feature pair. Packed single-shuffle per edge: u32 = (src<<16 | fp16(ex)).
// src < 50000 < 2^16; fp16 weight rel err 5e-4 << fp16-h error; denom stays fp32.
__global__ void agg_kernel(const int* __restrict__ sorted_src, const int* __restrict__ row_start,
                           const int* __restrict__ deg, const float* __restrict__ s_src,
                           const float* __restrict__ s_dst, const __half* __restrict__ h16,
                           const float* __restrict__ bias, float* __restrict__ out) {
  int gid = blockIdx.x * blockDim.x + threadIdx.x;
  int n = gid >> 5;
  if (n >= NN) return;
  int lane = threadIdx.x & 31;   // lane within the 32-lane group
  int start = row_start[n];
  int dg = deg[n];
  float sdn = s_dst[n];
  float sself = lrelu(s_src[n] + sdn);
  float exself = __expf(sself - 8.0f);

  float2 acc;
  {
    float2 f = __half22float2(*(const __half2*)&h16[(size_t)n * 64 + 2 * lane]);
    acc.x = exself * f.x;
    acc.y = exself * f.y;
  }
  float dpart = 0.0f;
  for (int base = 0; base < dg; base += 32) {
    int i = base + lane;
    bool act = (i < dg);
    int msrc = act ? __builtin_nontemporal_load(&sorted_src[start + i]) : 0;
    float s = act ? lrelu(s_src[msrc] + sdn) : -INFINITY;
    float ex = __expf(s - 8.0f);   // 0 for inactive lanes
    dpart += ex;
    unsigned pk = ((unsigned)msrc << 16) |
                  (unsigned)__half_as_ushort(__float2half_rn(ex));
    int nch = (dg - base < 32) ? (dg - base) : 32;
    for (int b0 = 0; b0 < nch; b0 += 8) {
      unsigned pu[8]; unsigned vv[8];
#pragma unroll
      for (int e = 0; e < 8; ++e)
        pu[e] = __shfl(pk, b0 + e, 32);
#pragma unroll
      for (int e = 0; e < 8; ++e)
        vv[e] = *(const unsigned*)&h16[(size_t)(pu[e] >> 16) * 64 + 2 * lane];
#pragma unroll
      for (int e = 0; e < 8; ++e) {
        float xf = __half2float(__ushort_as_half((unsigned short)(pu[e] & 0xFFFFu)));
        float2 f = __half22float2(*(__half2*)&vv[e]);
        acc.x = fmaf(xf, f.x, acc.x);
        acc.y = fmaf(xf, f.y, acc.y);
      }
    }
  }
#pragma unroll
  for (int off = 16; off > 0; off >>= 1)
    dpart += __shfl_xor(dpart, off, 32);
  float d = exself + dpart;
  float2 bv = *(const float2*)&bias[2 * lane];
  float2 o;
  o.x = acc.x / d + bv.x;
  o.y = acc.y / d + bv.y;
  *(float2*)&out[(size_t)n * 64 + 2 * lane] = o;
}

// ---------------- host-side orchestration --------------------------------------------

extern "C" void kernel_launch(void* const* d_in, const int* in_sizes, int n_in,
                              void* d_out, int out_size, void* d_ws, size_t ws_size,
                              hipStream_t stream) {
  const float* x  = (const float*)d_in[1];
  const int*   ei = (const int*)d_in[2];
  const float* W1 = (const float*)d_in[3];
  const float* as1 = (const float*)d_in[4];
  const float* ad1 = (const float*)d_in[5];
  const float* b1 = (const float*)d_in[6];
  const float* W2 = (const float*)d_in[7];
  const float* as2 = (const float*)d_in[8];
  const float* ad2 = (const float*)d_in[9];
  const float* b2 = (const float*)d_in[10];
  const float* W3 = (const float*)d_in[11];
  const float* as3 = (const float*)d_in[12];
  const float* ad3 = (const float*)d_in[13];
  const float* b3 = (const float*)d_in[14];
  float* out = (float*)d_out;

  const size_t ND = (size_t)NN * D;
  char* base = (char*)d_ws;
  __half* h16    = (__half*)base;                    // ND halves = 6.4 MB
  float* A       = (float*)(base + ND * 2);          // ND floats (12.8 MB)
  float* B       = A + ND;                           // ND floats
  float* s_src   = B + ND;                           // NN
  float* s_dst   = s_src + NN;                       // NN
  int* row_start = (int*)(s_dst + NN);               // NN
  int* deg       = row_start + NN;                   // NN
  int* gcur      = deg + NN;                         // NBUCK
  int* sorted_src= gcur + NBUCK;                     // NBUCK*CAPB = 6.4 MB
  // pairs aliases A: only live during CSR build, before agg1 writes A.
  unsigned* pairs = (unsigned*)A;                    // NBUCK*CAPB u32 = 6.4 MB (A is 12.8 MB)

  const int AGG_BLOCKS = (NN * 32 + 255) / 256;

  // ---- CSR bin + layer-1 GEMM fused (independent work) ----
  hipMemsetAsync(gcur, 0, (size_t)NBUCK * sizeof(int), stream);
  bin_gemm1<<<EBLKS + GB, 256, 0, stream>>>(ei, gcur, pairs, x, W1, as1, ad1,
                                            h16, s_src, s_dst);
  bucket_sort<<<NBUCK, 256, 0, stream>>>(pairs, gcur, row_start, deg, sorted_src);

  // ---- layer 1 aggregate ----
  agg_kernel<<<AGG_BLOCKS, 256, 0, stream>>>(sorted_src, row_start, deg, s_src, s_dst,
                                             h16, b1, A);
  // ---- layer 2 ----
  gemm_feat<<<GB, 256, 0, stream>>>(A, W2, as2, ad2, h16, s_src, s_dst, 1);
  agg_kernel<<<AGG_BLOCKS, 256, 0, stream>>>(sorted_src, row_start, deg, s_src, s_dst,
                                             h16, b2, B);
  // ---- layer 3 ----
  gemm_feat<<<GB, 256, 0, stream>>>(B, W3, as3, ad3, h16, s_src, s_dst, 1);
  agg_kernel<<<AGG_BLOCKS, 256, 0, stream>>>(sorted_src, row_start, deg, s_src, s_dst,
                                             h16, b3, out);
}